// Round 1
// baseline (1361.046 us; speedup 1.0000x reference)
//
#include <hip/hip_runtime.h>
#include <math.h>

// Problem: clDice loss. output (8,1,1024,1024) f32 logits, target (8,1,1024,1024) i32.
// loss = 0.5*soft_dice(sigmoid(out), tgt) + 0.5*soft_cldice(skel(sigmoid(out)), skel(tgt))
// skel: 10 iterations of erode/open morphology.
// erode(x) = min over cross {c, up, dn, lf, rt} (OOB ignored -> +inf)
// dilate(x) = max over 3x3 (OOB ignored -> -inf) ; open = dilate(erode(x))

#define HH 1024
#define WW 1024
#define BATCH 8
#define NPIX (BATCH * HH * WW)
#define NITER 10

__device__ __forceinline__ float fmin3(float a, float b, float c) { return fminf(a, fminf(b, c)); }
__device__ __forceinline__ float fmax3(float a, float b, float c) { return fmaxf(a, fmaxf(b, c)); }

// ---- block-wide 3-way sum reduction + atomic accumulate (256 threads = 4 waves) ----
__device__ __forceinline__ void block_reduce3_atomic(float a, float b, float c,
                                                     float* accA, float* accB, float* accC) {
    for (int off = 32; off > 0; off >>= 1) {
        a += __shfl_down(a, off);
        b += __shfl_down(b, off);
        c += __shfl_down(c, off);
    }
    __shared__ float sA[4], sB[4], sC[4];
    int lane = threadIdx.x & 63, wid = threadIdx.x >> 6;
    if (lane == 0) { sA[wid] = a; sB[wid] = b; sC[wid] = c; }
    __syncthreads();
    if (threadIdx.x == 0) {
        atomicAdd(accA, sA[0] + sA[1] + sA[2] + sA[3]);
        atomicAdd(accB, sB[0] + sB[1] + sB[2] + sB[3]);
        atomicAdd(accC, sC[0] + sC[1] + sC[2] + sC[3]);
    }
}

// ---- prep: probs = sigmoid(logits), tgtf = float(target); accumulate dice sums ----
__global__ __launch_bounds__(256) void prep_kernel(const float* __restrict__ logits,
                                                   const int* __restrict__ target,
                                                   float* __restrict__ probs,
                                                   float* __restrict__ tgtf,
                                                   float* __restrict__ acc) {
    int idx = blockIdx.x * 256 + threadIdx.x;  // one float4 per thread
    float4 x = ((const float4*)logits)[idx];
    int4 t = ((const int4*)target)[idx];
    float4 p;
    p.x = 1.0f / (1.0f + expf(-x.x));
    p.y = 1.0f / (1.0f + expf(-x.y));
    p.z = 1.0f / (1.0f + expf(-x.z));
    p.w = 1.0f / (1.0f + expf(-x.w));
    float4 tf = make_float4((float)t.x, (float)t.y, (float)t.z, (float)t.w);
    ((float4*)probs)[idx] = p;
    ((float4*)tgtf)[idx] = tf;
    float inter = p.x * tf.x + p.y * tf.y + p.z * tf.z + p.w * tf.w;
    float st = tf.x + tf.y + tf.z + tf.w;
    float card = p.x + p.y + p.z + p.w + st;
    block_reduce3_atomic(inter, card, st, acc + 0, acc + 1, acc + 2);
}

// ---- skel init: skel = relu(V - dilate(erode(V))). Tile 64x16, halo 2. ----
__global__ __launch_bounds__(256) void skel_init_kernel(const float* __restrict__ V,
                                                        float* __restrict__ skel) {
    __shared__ float imT[20 * 68];  // rows y0-2..y0+17, cols x0-2..x0+65 (OOB=+inf)
    __shared__ float s1[18 * 66];   // erode(V), OOB=-inf (feeds dilate)
    int img = blockIdx.z;
    int x0 = blockIdx.x * 64, y0 = blockIdx.y * 16;
    const float* base = V + (size_t)img * HH * WW;
    int tid = threadIdx.x;
    for (int li = tid; li < 20 * 68; li += 256) {
        int i = li / 68, j = li % 68;
        int gy = y0 - 2 + i, gx = x0 - 2 + j;
        imT[li] = (gy >= 0 && gy < HH && gx >= 0 && gx < WW) ? base[gy * WW + gx] : INFINITY;
    }
    __syncthreads();
    for (int li = tid; li < 18 * 66; li += 256) {
        int i = li / 66, j = li % 66;
        int gy = y0 - 1 + i, gx = x0 - 1 + j;
        float v;
        if (gy >= 0 && gy < HH && gx >= 0 && gx < WW) {
            const float* p = &imT[(i + 1) * 68 + (j + 1)];
            v = fminf(fmin3(p[-1], p[0], p[1]), fminf(p[-68], p[68]));
        } else v = -INFINITY;
        s1[li] = v;
    }
    __syncthreads();
    int orow = tid >> 4, oc = (tid & 15) * 4;
    float r[4];
    for (int k = 0; k < 4; k++) {
        const float* p = &s1[(orow + 1) * 66 + (oc + k + 1)];
        float open = fmax3(p[-1], p[0], p[1]);
        open = fmaxf(open, fmax3(p[-67], p[-66], p[-65]));
        open = fmaxf(open, fmax3(p[65], p[66], p[67]));
        float v = imT[(orow + 2) * 68 + (oc + k + 2)];
        r[k] = fmaxf(v - open, 0.0f);
    }
    size_t goff = (size_t)img * HH * WW + (size_t)(y0 + orow) * WW + (x0 + oc);
    *(float4*)(skel + goff) = make_float4(r[0], r[1], r[2], r[3]);
}

// ---- skel iteration, fully fused (halo 3):
//   im' = erode(im); open = dilate(erode(im')); delta = relu(im'-open);
//   skel += relu(delta - skel*delta); Xnew = im'
__global__ __launch_bounds__(256) void skel_iter_kernel(const float* __restrict__ X,
                                                        float* __restrict__ Xnew,
                                                        float* __restrict__ skel) {
    __shared__ float imT[22 * 70];  // halo 3, OOB=+inf
    __shared__ float s1[20 * 68];   // erode(X) = im', OOB=+inf (feeds erode)
    __shared__ float s2[18 * 66];   // erode(im'), OOB=-inf (feeds dilate)
    int img = blockIdx.z;
    int x0 = blockIdx.x * 64, y0 = blockIdx.y * 16;
    const float* base = X + (size_t)img * HH * WW;
    int tid = threadIdx.x;
    for (int li = tid; li < 22 * 70; li += 256) {
        int i = li / 70, j = li % 70;
        int gy = y0 - 3 + i, gx = x0 - 3 + j;
        imT[li] = (gy >= 0 && gy < HH && gx >= 0 && gx < WW) ? base[gy * WW + gx] : INFINITY;
    }
    __syncthreads();
    for (int li = tid; li < 20 * 68; li += 256) {
        int i = li / 68, j = li % 68;
        int gy = y0 - 2 + i, gx = x0 - 2 + j;
        float v;
        if (gy >= 0 && gy < HH && gx >= 0 && gx < WW) {
            const float* p = &imT[(i + 1) * 70 + (j + 1)];
            v = fminf(fmin3(p[-1], p[0], p[1]), fminf(p[-70], p[70]));
        } else v = INFINITY;
        s1[li] = v;
    }
    __syncthreads();
    for (int li = tid; li < 18 * 66; li += 256) {
        int i = li / 66, j = li % 66;
        int gy = y0 - 1 + i, gx = x0 - 1 + j;
        float v;
        if (gy >= 0 && gy < HH && gx >= 0 && gx < WW) {
            const float* p = &s1[(i + 1) * 68 + (j + 1)];
            v = fminf(fmin3(p[-1], p[0], p[1]), fminf(p[-68], p[68]));
        } else v = -INFINITY;
        s2[li] = v;
    }
    __syncthreads();
    int orow = tid >> 4, oc = (tid & 15) * 4;
    size_t goff = (size_t)img * HH * WW + (size_t)(y0 + orow) * WW + (x0 + oc);
    float4 sk = *(const float4*)(skel + goff);
    float skv[4] = {sk.x, sk.y, sk.z, sk.w};
    float ri[4], rs[4];
    for (int k = 0; k < 4; k++) {
        const float* p = &s2[(orow + 1) * 66 + (oc + k + 1)];
        float open = fmax3(p[-1], p[0], p[1]);
        open = fmaxf(open, fmax3(p[-67], p[-66], p[-65]));
        open = fmaxf(open, fmax3(p[65], p[66], p[67]));
        float imn = s1[(orow + 2) * 68 + (oc + k + 2)];
        float delta = fmaxf(imn - open, 0.0f);
        rs[k] = skv[k] + fmaxf(delta - skv[k] * delta, 0.0f);
        ri[k] = imn;
    }
    *(float4*)(Xnew + goff) = make_float4(ri[0], ri[1], ri[2], ri[3]);
    *(float4*)(skel + goff) = make_float4(rs[0], rs[1], rs[2], rs[3]);
}

// ---- cldice reduction: I = sum(so*st), So = sum(so), St = sum(st) ----
__global__ __launch_bounds__(256) void cl_reduce_kernel(const float* __restrict__ so,
                                                        const float* __restrict__ st,
                                                        float* __restrict__ acc) {
    int idx = blockIdx.x * 256 + threadIdx.x;
    float4 a = ((const float4*)so)[idx];
    float4 b = ((const float4*)st)[idx];
    float I = a.x * b.x + a.y * b.y + a.z * b.z + a.w * b.w;
    float So = a.x + a.y + a.z + a.w;
    float St = b.x + b.y + b.z + b.w;
    block_reduce3_atomic(I, So, St, acc + 3, acc + 4, acc + 5);
}

// ---- final scalar ----
__global__ void final_kernel(const float* __restrict__ acc, float* __restrict__ out) {
    float inter = acc[0], card = acc[1], sumt = acc[2];
    float I = acc[3], So = acc[4], St = acc[5];
    float score_d = (2.0f * inter + 1.0f) / fmaxf(card + 1.0f, 1e-7f);
    float dice = (1.0f - score_d) * (sumt > 0.0f ? 1.0f : 0.0f);
    float tprec = (I + 1.0f) / (So + 1.0f);
    float tsens = (I + 1.0f) / (St + 1.0f);
    float score_c = 2.0f * (tprec * tsens) / (tprec + tsens);
    float cl = (1.0f - score_c) * (St > 0.0f ? 1.0f : 0.0f);
    out[0] = 0.5f * dice + 0.5f * cl;
}

extern "C" void kernel_launch(void* const* d_in, const int* in_sizes, int n_in,
                              void* d_out, int out_size, void* d_ws, size_t ws_size,
                              hipStream_t stream) {
    const float* logits = (const float*)d_in[0];
    const int* target = (const int*)d_in[1];
    float* out = (float*)d_out;

    float* acc = (float*)d_ws;        // 64 floats scratch (6 used)
    float* buf0 = acc + 64;           // probs / later skel_t
    float* buf1 = buf0 + (size_t)NPIX;  // ping-pong / later skel_t
    float* buf2 = buf1 + (size_t)NPIX;  // skel_o
    float* buf3 = buf2 + (size_t)NPIX;  // tgtf / ping-pong

    hipMemsetAsync(d_ws, 0, 64 * sizeof(float), stream);

    dim3 gtile(WW / 64, HH / 16, BATCH);  // (16, 64, 8)
    dim3 b256(256);

    // prep: probs->buf0, tgtf->buf3, dice sums->acc[0..2]
    prep_kernel<<<NPIX / 1024, b256, 0, stream>>>(logits, target, buf0, buf3, acc);

    // ---- image o: X=buf0 ping-pong with buf1, skel_o=buf2 ----
    skel_init_kernel<<<gtile, b256, 0, stream>>>(buf0, buf2);
    {
        float* X = buf0;
        float* Y = buf1;
        for (int it = 0; it < NITER; ++it) {
            skel_iter_kernel<<<gtile, b256, 0, stream>>>(X, Y, buf2);
            float* t = X; X = Y; Y = t;
        }
    }

    // ---- image t: X=buf3 ping-pong with buf0, skel_t=buf1 ----
    skel_init_kernel<<<gtile, b256, 0, stream>>>(buf3, buf1);
    {
        float* X = buf3;
        float* Y = buf0;
        for (int it = 0; it < NITER; ++it) {
            skel_iter_kernel<<<gtile, b256, 0, stream>>>(X, Y, buf1);
            float* t = X; X = Y; Y = t;
        }
    }

    // ---- cldice sums: acc[3..5] ----
    cl_reduce_kernel<<<NPIX / 1024, b256, 0, stream>>>(buf2, buf1, acc);

    final_kernel<<<1, 1, 0, stream>>>(acc, out);
}

// Round 2
// 775.084 us; speedup vs baseline: 1.7560x; 1.7560x over previous
//
#include <hip/hip_runtime.h>
#include <math.h>

// Problem: clDice loss. output (8,1,1024,1024) f32 logits, target (8,1,1024,1024) i32.
// loss = 0.5*soft_dice(sigmoid(out), tgt) + 0.5*soft_cldice(skel(sigmoid(out)), skel(tgt))
// skel: 10 iterations of erode/open morphology.
// erode(x) = min over cross {c, up, dn, lf, rt} (OOB ignored -> +inf)
// dilate(x) = max over 3x3 (OOB ignored -> -inf) ; open = dilate(erode(x))
//
// R2: removed same-address atomicAdd reductions (R1 profile: prep_kernel 320us at
// 317 GB/s, VALUBusy 2.9% -> 24k same-line device atomics serialized ~300us).
// Now per-block partials (no atomics) + tiny 1-block reduce kernels.

#define HH 1024
#define WW 1024
#define BATCH 8
#define NPIX (BATCH * HH * WW)
#define NITER 10
#define NB (NPIX / 1024)  // 8192 blocks for flat reduction kernels

__device__ __forceinline__ float fmin3(float a, float b, float c) { return fminf(a, fminf(b, c)); }
__device__ __forceinline__ float fmax3(float a, float b, float c) { return fmaxf(a, fmaxf(b, c)); }

// ---- block-wide 3-way sum reduction; results valid on thread 0 ----
__device__ __forceinline__ void block_reduce3(float& a, float& b, float& c) {
    for (int off = 32; off > 0; off >>= 1) {
        a += __shfl_down(a, off);
        b += __shfl_down(b, off);
        c += __shfl_down(c, off);
    }
    __shared__ float sA[4], sB[4], sC[4];
    int lane = threadIdx.x & 63, wid = threadIdx.x >> 6;
    if (lane == 0) { sA[wid] = a; sB[wid] = b; sC[wid] = c; }
    __syncthreads();
    if (threadIdx.x == 0) {
        a = sA[0] + sA[1] + sA[2] + sA[3];
        b = sB[0] + sB[1] + sB[2] + sB[3];
        c = sC[0] + sC[1] + sC[2] + sC[3];
    }
}

// ---- prep: probs = sigmoid(logits), tgtf = float(target); per-block dice partials ----
__global__ __launch_bounds__(256) void prep_kernel(const float* __restrict__ logits,
                                                   const int* __restrict__ target,
                                                   float* __restrict__ probs,
                                                   float* __restrict__ tgtf,
                                                   float* __restrict__ partials) {
    int idx = blockIdx.x * 256 + threadIdx.x;  // one float4 per thread
    float4 x = ((const float4*)logits)[idx];
    int4 t = ((const int4*)target)[idx];
    float4 p;
    p.x = 1.0f / (1.0f + expf(-x.x));
    p.y = 1.0f / (1.0f + expf(-x.y));
    p.z = 1.0f / (1.0f + expf(-x.z));
    p.w = 1.0f / (1.0f + expf(-x.w));
    float4 tf = make_float4((float)t.x, (float)t.y, (float)t.z, (float)t.w);
    ((float4*)probs)[idx] = p;
    ((float4*)tgtf)[idx] = tf;
    float inter = p.x * tf.x + p.y * tf.y + p.z * tf.z + p.w * tf.w;
    float st = tf.x + tf.y + tf.z + tf.w;
    float card = p.x + p.y + p.z + p.w + st;
    block_reduce3(inter, card, st);
    if (threadIdx.x == 0) {
        partials[blockIdx.x] = inter;
        partials[NB + blockIdx.x] = card;
        partials[2 * NB + blockIdx.x] = st;
    }
}

// ---- reduce prep partials -> acc[0..2] ----
__global__ __launch_bounds__(256) void partial_reduce_kernel(const float* __restrict__ partials,
                                                             float* __restrict__ acc) {
    float a = 0.f, b = 0.f, c = 0.f;
    for (int i = threadIdx.x; i < NB; i += 256) {
        a += partials[i];
        b += partials[NB + i];
        c += partials[2 * NB + i];
    }
    block_reduce3(a, b, c);
    if (threadIdx.x == 0) { acc[0] = a; acc[1] = b; acc[2] = c; }
}

// ---- skel init: skel = relu(V - dilate(erode(V))). Tile 64x16, halo 2. ----
__global__ __launch_bounds__(256) void skel_init_kernel(const float* __restrict__ V,
                                                        float* __restrict__ skel) {
    __shared__ float imT[20 * 68];  // rows y0-2..y0+17, cols x0-2..x0+65 (OOB=+inf)
    __shared__ float s1[18 * 66];   // erode(V), OOB=-inf (feeds dilate)
    int img = blockIdx.z;
    int x0 = blockIdx.x * 64, y0 = blockIdx.y * 16;
    const float* base = V + (size_t)img * HH * WW;
    int tid = threadIdx.x;
    for (int li = tid; li < 20 * 68; li += 256) {
        int i = li / 68, j = li % 68;
        int gy = y0 - 2 + i, gx = x0 - 2 + j;
        imT[li] = (gy >= 0 && gy < HH && gx >= 0 && gx < WW) ? base[gy * WW + gx] : INFINITY;
    }
    __syncthreads();
    for (int li = tid; li < 18 * 66; li += 256) {
        int i = li / 66, j = li % 66;
        int gy = y0 - 1 + i, gx = x0 - 1 + j;
        float v;
        if (gy >= 0 && gy < HH && gx >= 0 && gx < WW) {
            const float* p = &imT[(i + 1) * 68 + (j + 1)];
            v = fminf(fmin3(p[-1], p[0], p[1]), fminf(p[-68], p[68]));
        } else v = -INFINITY;
        s1[li] = v;
    }
    __syncthreads();
    int orow = tid >> 4, oc = (tid & 15) * 4;
    float r[4];
    for (int k = 0; k < 4; k++) {
        const float* p = &s1[(orow + 1) * 66 + (oc + k + 1)];
        float open = fmax3(p[-1], p[0], p[1]);
        open = fmaxf(open, fmax3(p[-67], p[-66], p[-65]));
        open = fmaxf(open, fmax3(p[65], p[66], p[67]));
        float v = imT[(orow + 2) * 68 + (oc + k + 2)];
        r[k] = fmaxf(v - open, 0.0f);
    }
    size_t goff = (size_t)img * HH * WW + (size_t)(y0 + orow) * WW + (x0 + oc);
    *(float4*)(skel + goff) = make_float4(r[0], r[1], r[2], r[3]);
}

// ---- skel iteration, fully fused (halo 3):
//   im' = erode(im); open = dilate(erode(im')); delta = relu(im'-open);
//   skel += relu(delta - skel*delta); Xnew = im'
__global__ __launch_bounds__(256) void skel_iter_kernel(const float* __restrict__ X,
                                                        float* __restrict__ Xnew,
                                                        float* __restrict__ skel) {
    __shared__ float imT[22 * 70];  // halo 3, OOB=+inf
    __shared__ float s1[20 * 68];   // erode(X) = im', OOB=+inf (feeds erode)
    __shared__ float s2[18 * 66];   // erode(im'), OOB=-inf (feeds dilate)
    int img = blockIdx.z;
    int x0 = blockIdx.x * 64, y0 = blockIdx.y * 16;
    const float* base = X + (size_t)img * HH * WW;
    int tid = threadIdx.x;
    for (int li = tid; li < 22 * 70; li += 256) {
        int i = li / 70, j = li % 70;
        int gy = y0 - 3 + i, gx = x0 - 3 + j;
        imT[li] = (gy >= 0 && gy < HH && gx >= 0 && gx < WW) ? base[gy * WW + gx] : INFINITY;
    }
    __syncthreads();
    for (int li = tid; li < 20 * 68; li += 256) {
        int i = li / 68, j = li % 68;
        int gy = y0 - 2 + i, gx = x0 - 2 + j;
        float v;
        if (gy >= 0 && gy < HH && gx >= 0 && gx < WW) {
            const float* p = &imT[(i + 1) * 70 + (j + 1)];
            v = fminf(fmin3(p[-1], p[0], p[1]), fminf(p[-70], p[70]));
        } else v = INFINITY;
        s1[li] = v;
    }
    __syncthreads();
    for (int li = tid; li < 18 * 66; li += 256) {
        int i = li / 66, j = li % 66;
        int gy = y0 - 1 + i, gx = x0 - 1 + j;
        float v;
        if (gy >= 0 && gy < HH && gx >= 0 && gx < WW) {
            const float* p = &s1[(i + 1) * 68 + (j + 1)];
            v = fminf(fmin3(p[-1], p[0], p[1]), fminf(p[-68], p[68]));
        } else v = -INFINITY;
        s2[li] = v;
    }
    __syncthreads();
    int orow = tid >> 4, oc = (tid & 15) * 4;
    size_t goff = (size_t)img * HH * WW + (size_t)(y0 + orow) * WW + (x0 + oc);
    float4 sk = *(const float4*)(skel + goff);
    float skv[4] = {sk.x, sk.y, sk.z, sk.w};
    float ri[4], rs[4];
    for (int k = 0; k < 4; k++) {
        const float* p = &s2[(orow + 1) * 66 + (oc + k + 1)];
        float open = fmax3(p[-1], p[0], p[1]);
        open = fmaxf(open, fmax3(p[-67], p[-66], p[-65]));
        open = fmaxf(open, fmax3(p[65], p[66], p[67]));
        float imn = s1[(orow + 2) * 68 + (oc + k + 2)];
        float delta = fmaxf(imn - open, 0.0f);
        rs[k] = skv[k] + fmaxf(delta - skv[k] * delta, 0.0f);
        ri[k] = imn;
    }
    *(float4*)(Xnew + goff) = make_float4(ri[0], ri[1], ri[2], ri[3]);
    *(float4*)(skel + goff) = make_float4(rs[0], rs[1], rs[2], rs[3]);
}

// ---- cldice reduction: per-block partials of I = sum(so*st), So = sum(so), St = sum(st) ----
__global__ __launch_bounds__(256) void cl_reduce_kernel(const float* __restrict__ so,
                                                        const float* __restrict__ st,
                                                        float* __restrict__ partials) {
    int idx = blockIdx.x * 256 + threadIdx.x;
    float4 a = ((const float4*)so)[idx];
    float4 b = ((const float4*)st)[idx];
    float I = a.x * b.x + a.y * b.y + a.z * b.z + a.w * b.w;
    float So = a.x + a.y + a.z + a.w;
    float St = b.x + b.y + b.z + b.w;
    block_reduce3(I, So, St);
    if (threadIdx.x == 0) {
        partials[blockIdx.x] = I;
        partials[NB + blockIdx.x] = So;
        partials[2 * NB + blockIdx.x] = St;
    }
}

// ---- final: reduce cl partials + combine with dice acc -> loss ----
__global__ __launch_bounds__(256) void final_kernel(const float* __restrict__ partials,
                                                    const float* __restrict__ acc,
                                                    float* __restrict__ out) {
    float I = 0.f, So = 0.f, St = 0.f;
    for (int i = threadIdx.x; i < NB; i += 256) {
        I += partials[i];
        So += partials[NB + i];
        St += partials[2 * NB + i];
    }
    block_reduce3(I, So, St);
    if (threadIdx.x == 0) {
        float inter = acc[0], card = acc[1], sumt = acc[2];
        float score_d = (2.0f * inter + 1.0f) / fmaxf(card + 1.0f, 1e-7f);
        float dice = (1.0f - score_d) * (sumt > 0.0f ? 1.0f : 0.0f);
        float tprec = (I + 1.0f) / (So + 1.0f);
        float tsens = (I + 1.0f) / (St + 1.0f);
        float score_c = 2.0f * (tprec * tsens) / (tprec + tsens);
        float cl = (1.0f - score_c) * (St > 0.0f ? 1.0f : 0.0f);
        out[0] = 0.5f * dice + 0.5f * cl;
    }
}

extern "C" void kernel_launch(void* const* d_in, const int* in_sizes, int n_in,
                              void* d_out, int out_size, void* d_ws, size_t ws_size,
                              hipStream_t stream) {
    const float* logits = (const float*)d_in[0];
    const int* target = (const int*)d_in[1];
    float* out = (float*)d_out;

    float* acc = (float*)d_ws;          // 64 floats persistent scalars (3 used)
    float* buf0 = acc + 64;             // probs / t-phase ping-pong / cl partials
    float* buf1 = buf0 + (size_t)NPIX;  // o-phase ping-pong / skel_t ; head = prep partials
    float* buf2 = buf1 + (size_t)NPIX;  // skel_o
    float* buf3 = buf2 + (size_t)NPIX;  // tgtf / t-phase ping-pong

    dim3 gtile(WW / 64, HH / 16, BATCH);  // (16, 64, 8)
    dim3 b256(256);

    // prep: probs->buf0, tgtf->buf3, dice partials -> head of buf1 (dead until o-iter0)
    prep_kernel<<<NB, b256, 0, stream>>>(logits, target, buf0, buf3, buf1);
    partial_reduce_kernel<<<1, b256, 0, stream>>>(buf1, acc);

    // ---- image o: X=buf0 ping-pong with buf1, skel_o=buf2 ----
    skel_init_kernel<<<gtile, b256, 0, stream>>>(buf0, buf2);
    {
        float* X = buf0;
        float* Y = buf1;
        for (int it = 0; it < NITER; ++it) {
            skel_iter_kernel<<<gtile, b256, 0, stream>>>(X, Y, buf2);
            float* t = X; X = Y; Y = t;
        }
    }

    // ---- image t: X=buf3 ping-pong with buf0, skel_t=buf1 ----
    skel_init_kernel<<<gtile, b256, 0, stream>>>(buf3, buf1);
    {
        float* X = buf3;
        float* Y = buf0;
        for (int it = 0; it < NITER; ++it) {
            skel_iter_kernel<<<gtile, b256, 0, stream>>>(X, Y, buf1);
            float* t = X; X = Y; Y = t;
        }
    }

    // ---- cldice partials -> head of buf0 (dead: last t-iter wrote buf3) ----
    cl_reduce_kernel<<<NB, b256, 0, stream>>>(buf2, buf1, buf0);
    final_kernel<<<1, b256, 0, stream>>>(buf0, acc, out);
}